// Round 4
// baseline (259.411 us; speedup 1.0000x reference)
//
#include <hip/hip_runtime.h>

static constexpr int C  = 512;
static constexpr int P  = 4096;    // H*W
static constexpr int CC = 262144;  // 512*512

typedef _Float16 half8  __attribute__((ext_vector_type(8)));
typedef _Float16 half2v __attribute__((ext_vector_type(2)));
typedef float    f32x4  __attribute__((ext_vector_type(4)));

__device__ __forceinline__ int refl(int q) { return q < 0 ? 1 : (q > 63 ? 62 : q); }

__device__ __forceinline__ void g2l16(const void* g, const void* l) {
    __builtin_amdgcn_global_load_lds((const __attribute__((address_space(1))) unsigned int*)g,
                                     (__attribute__((address_space(3))) unsigned int*)l, 16, 0, 0);
}

// small layout (floats): sqn_s[0..4095], inv_sn[4096..8191], msum@8192, acc@8193,
// cnt_prep@8194 (u32), cnt_loss@8195 (u32), idx@8196..12291 (int)

// ---------------- zero scratch that must start at 0 ----------------
__global__ void k_init(float* __restrict__ small) {
    int e = blockIdx.x * 256 + threadIdx.x;
    if (e < 4096) small[e] = 0.0f;          // sqn_s
    if (e == 0) {
        small[8193] = 0.0f;                  // acc
        ((unsigned*)small)[8194] = 0u;       // cnt_prep
        ((unsigned*)small)[8195] = 0u;       // cnt_loss
    }
}

// ---------------- transpose fp32 [c][p] -> fp16 [p][c]; style sq-norm; last block: pnorm+msum ----------------
__global__ __launch_bounds__(256) void k_prep(const float* __restrict__ content, const float* __restrict__ style,
                                              const float* __restrict__ mask,
                                              _Float16* __restrict__ Ah, _Float16* __restrict__ Bh,
                                              float* __restrict__ sqn_s, float* __restrict__ inv_sn,
                                              float* __restrict__ msum, unsigned* __restrict__ cnt) {
    __shared__ float T[64][65];
    const int p0 = (blockIdx.x & 63) * 64, c0 = (blockIdx.x >> 6) * 64;
    const int pl = threadIdx.x & 63, cq = threadIdx.x >> 6;   // read role
    const int cl2 = threadIdx.x & 63, pq = threadIdx.x >> 6;  // write role

    // content (c_norm dropped from argmax: constant over j)
    #pragma unroll
    for (int r = 0; r < 16; ++r) {
        int cl = cq + r * 4;
        T[cl][pl] = content[(size_t)(c0 + cl) * P + p0 + pl];
    }
    __syncthreads();
    #pragma unroll
    for (int r = 0; r < 16; ++r) {
        int pl2 = pq + r * 4;
        Ah[(size_t)(p0 + pl2) * C + c0 + cl2] = (_Float16)T[cl2][pl2];
    }
    __syncthreads();

    // style
    float sq = 0.f;
    #pragma unroll
    for (int r = 0; r < 16; ++r) {
        int cl = cq + r * 4;
        float v = style[(size_t)(c0 + cl) * P + p0 + pl];
        T[cl][pl] = v;
        sq += v * v;
    }
    atomicAdd(&sqn_s[p0 + pl], sq);
    __syncthreads();
    #pragma unroll
    for (int r = 0; r < 16; ++r) {
        int pl2 = pq + r * 4;
        Bh[(size_t)(p0 + pl2) * C + c0 + cl2] = (_Float16)T[cl2][pl2];
    }

    // last-done block computes inv_sn + msum (saves a kernel launch)
    __threadfence();
    __syncthreads();
    __shared__ unsigned lastv;
    if (threadIdx.x == 0) lastv = atomicAdd(cnt, 1);
    __syncthreads();
    if (lastv == 511) {
        __shared__ float sqs[4096];
        for (int r = threadIdx.x; r < 4096; r += 256)
            sqs[r] = __hip_atomic_load(&sqn_s[r], __ATOMIC_RELAXED, __HIP_MEMORY_SCOPE_AGENT);
        __syncthreads();
        for (int r = threadIdx.x; r < 4096; r += 256) {
            int i = r >> 6, j = r & 63;
            float s2 = 0.f;
            #pragma unroll
            for (int dh = -1; dh <= 1; ++dh) {
                int ih = refl(i + dh);
                #pragma unroll
                for (int dw = -1; dw <= 1; ++dw)
                    s2 += sqs[ih * 64 + refl(j + dw)];
            }
            inv_sn[r] = 1.0f / sqrtf(s2);
        }
        __shared__ float red[256];
        float s = 0.f;
        for (int e = threadIdx.x; e < 4096; e += 256) s += mask[e];
        red[threadIdx.x] = s;
        __syncthreads();
        for (int t = 128; t > 0; t >>= 1) {
            if (threadIdx.x < t) red[threadIdx.x] += red[threadIdx.x + t];
            __syncthreads();
        }
        if (threadIdx.x == 0) msum[0] = red[0];
    }
}

// ---------------- D0 = Ah * Bh^T (4096x4096, K=512), fp16 MFMA, BK=64 m97-style ----------------
__global__ __launch_bounds__(256) void k_gemm16(const _Float16* __restrict__ Ah,
                                                const _Float16* __restrict__ Bh,
                                                _Float16* __restrict__ D0h) {
    __shared__ _Float16 As[128 * 64];
    __shared__ _Float16 Bs[128 * 64];
    const int tid = threadIdx.x;
    const int wave = tid >> 6, lane = tid & 63;
    const int wr = wave >> 1, wc = wave & 1;
    const int quad = lane >> 4, l15 = lane & 15;
    const int i0 = blockIdx.y * 128, j0 = blockIdx.x * 128;

    int mloc[4], goff[4];
    #pragma unroll
    for (int c2 = 0; c2 < 4; ++c2) {
        int m = wave * 32 + c2 * 8 + (lane >> 3);
        mloc[c2] = m;
        goff[c2] = ((lane & 7) ^ (m & 7)) * 8;
    }

    int aoff[4][2], boff[4][2];
    #pragma unroll
    for (int mi = 0; mi < 4; ++mi) {
        int m = wr * 64 + mi * 16 + l15;
        int n = wc * 64 + mi * 16 + l15;
        #pragma unroll
        for (int kh = 0; kh < 2; ++kh) {
            aoff[mi][kh] = m * 64 + ((quad + kh * 4) ^ (m & 7)) * 8;
            boff[mi][kh] = n * 64 + ((quad + kh * 4) ^ (n & 7)) * 8;
        }
    }

    f32x4 acc[4][4] = {};

    for (int kk = 0; kk < C; kk += 64) {
        __syncthreads();
        #pragma unroll
        for (int c2 = 0; c2 < 4; ++c2) {
            g2l16(Ah + (size_t)(i0 + mloc[c2]) * C + kk + goff[c2], As + (wave * 32 + c2 * 8) * 64);
            g2l16(Bh + (size_t)(j0 + mloc[c2]) * C + kk + goff[c2], Bs + (wave * 32 + c2 * 8) * 64);
        }
        __syncthreads();
        half8 af[2][4], bf[2][4];
        #pragma unroll
        for (int kh = 0; kh < 2; ++kh)
            #pragma unroll
            for (int mi = 0; mi < 4; ++mi) {
                af[kh][mi] = *(const half8*)(As + aoff[mi][kh]);
                bf[kh][mi] = *(const half8*)(Bs + boff[mi][kh]);
            }
        #pragma unroll
        for (int kh = 0; kh < 2; ++kh)
            #pragma unroll
            for (int mi = 0; mi < 4; ++mi)
                #pragma unroll
                for (int ni = 0; ni < 4; ++ni)
                    acc[mi][ni] = __builtin_amdgcn_mfma_f32_16x16x32_f16(af[kh][mi], bf[kh][ni], acc[mi][ni], 0, 0, 0);
    }

    #pragma unroll
    for (int mi = 0; mi < 4; ++mi) {
        int row = i0 + wr * 64 + mi * 16 + quad * 4;
        #pragma unroll
        for (int ni = 0; ni < 4; ++ni) {
            int col = j0 + wc * 64 + ni * 16 + l15;
            #pragma unroll
            for (int r = 0; r < 4; ++r)
                D0h[(size_t)(row + r) * P + col] = (_Float16)acc[mi][ni][r];
        }
    }
}

// ---------------- 9-shift score + argmax, 2x2 i-tile per block (16-row union vs 36) ----------------
__global__ __launch_bounds__(256) void k_argmax(const _Float16* __restrict__ D0h,
                                                const float* __restrict__ inv_sn,
                                                int* __restrict__ idxOut) {
    const int T = blockIdx.x;                 // 1024 tiles
    const int ih0 = (T >> 5) * 2, iw0 = (T & 31) * 2;
    const int wave = threadIdx.x >> 6, l = threadIdx.x & 63, l15 = l & 15;

    int rh[4], rw[4];
    rh[0] = refl(ih0 - 1); rh[1] = ih0; rh[2] = ih0 + 1; rh[3] = refl(ih0 + 2);
    rw[0] = refl(iw0 - 1); rw[1] = iw0; rw[2] = iw0 + 1; rw[3] = refl(iw0 + 2);
    int rb[3][2][4];
    #pragma unroll
    for (int d = 0; d < 3; ++d)
        #pragma unroll
        for (int di = 0; di < 2; ++di)
            #pragma unroll
            for (int k = 0; k < 4; ++k)
                rb[d][di][k] = (rh[di + d] * 64 + rw[k]) * P;

    float best[2][2] = {{-1e30f, -1e30f}, {-1e30f, -1e30f}};
    int   bidx[2][2] = {{0, 0}, {0, 0}};

    #pragma unroll
    for (int s = 0; s < 4; ++s) {
        const int ws = wave * 4 + s;
        const int j0 = ws * 256 + l * 4;
        const int jh = j0 >> 6;
        const int jw0 = l15 * 4;
        const int rs0 = (jh == 0) ? 1 : jh - 1;
        const int rs2 = (jh == 63) ? 62 : jh + 1;
        const int cb[3] = { rs0 * 64 + jw0, jh * 64 + jw0, rs2 * 64 + jw0 };

        float f[2][2][4] = {};
        #pragma unroll
        for (int d = 0; d < 3; ++d) {
            #pragma unroll
            for (int di = 0; di < 2; ++di) {
                uint2 u[4];
                #pragma unroll
                for (int k = 0; k < 4; ++k)
                    u[k] = *(const uint2*)(D0h + rb[d][di][k] + cb[d]);
                #pragma unroll
                for (int dj = 0; dj < 2; ++dj) {
                    const uint2 A = u[dj], Bc = u[dj + 1], Cc = u[dj + 2];
                    unsigned prev_hi = (unsigned)__shfl((int)A.y, l - 1);
                    unsigned next_lo = (unsigned)__shfl((int)Cc.x, l + 1);
                    unsigned left16  = ((l15 == 0) ? A.x : prev_hi) >> 16;
                    unsigned right16 = ((l15 == 15) ? Cc.y : next_lo) & 0xffffu;
                    unsigned wl0 = left16 | (A.x << 16);
                    unsigned wl1 = (A.x >> 16) | (A.y << 16);
                    unsigned wr0 = (Cc.x >> 16) | (Cc.y << 16);
                    unsigned wr1 = (Cc.y >> 16) | (right16 << 16);
                    half2v a0 = __builtin_bit_cast(half2v, wl0), a1 = __builtin_bit_cast(half2v, wl1);
                    half2v b0 = __builtin_bit_cast(half2v, Bc.x), b1 = __builtin_bit_cast(half2v, Bc.y);
                    half2v c0 = __builtin_bit_cast(half2v, wr0), c1 = __builtin_bit_cast(half2v, wr1);
                    f[di][dj][0] += (float)a0[0] + (float)b0[0] + (float)c0[0];
                    f[di][dj][1] += (float)a0[1] + (float)b0[1] + (float)c0[1];
                    f[di][dj][2] += (float)a1[0] + (float)b1[0] + (float)c1[0];
                    f[di][dj][3] += (float)a1[1] + (float)b1[1] + (float)c1[1];
                }
            }
        }
        const float4 is = *(const float4*)(inv_sn + j0);
        #pragma unroll
        for (int di = 0; di < 2; ++di)
            #pragma unroll
            for (int dj = 0; dj < 2; ++dj) {
                float v0 = f[di][dj][0] * is.x, v1 = f[di][dj][1] * is.y;
                float v2 = f[di][dj][2] * is.z, v3 = f[di][dj][3] * is.w;
                if (v0 > best[di][dj]) { best[di][dj] = v0; bidx[di][dj] = j0; }
                if (v1 > best[di][dj]) { best[di][dj] = v1; bidx[di][dj] = j0 + 1; }
                if (v2 > best[di][dj]) { best[di][dj] = v2; bidx[di][dj] = j0 + 2; }
                if (v3 > best[di][dj]) { best[di][dj] = v3; bidx[di][dj] = j0 + 3; }
            }
    }

    __shared__ float bv[256];
    __shared__ int   bi[256];
    #pragma unroll
    for (int di = 0; di < 2; ++di)
        #pragma unroll
        for (int dj = 0; dj < 2; ++dj) {
            __syncthreads();
            bv[threadIdx.x] = best[di][dj];
            bi[threadIdx.x] = bidx[di][dj];
            __syncthreads();
            for (int t = 128; t > 0; t >>= 1) {
                if (threadIdx.x < t) {
                    float ov = bv[threadIdx.x + t];
                    int   oi = bi[threadIdx.x + t];
                    if (ov > bv[threadIdx.x] || (ov == bv[threadIdx.x] && oi < bi[threadIdx.x])) {
                        bv[threadIdx.x] = ov;
                        bi[threadIdx.x] = oi;
                    }
                }
                __syncthreads();
            }
            if (threadIdx.x == 0) idxOut[(ih0 + di) * 64 + iw0 + dj] = bi[0];
        }
}

// ---------------- build masked fp16 matrices ----------------
__global__ void k_build(const float* __restrict__ style, const float* __restrict__ input,
                        const float* __restrict__ mask, const int* __restrict__ idx,
                        _Float16* __restrict__ fc, _Float16* __restrict__ fg) {
    int t = blockIdx.x * 256 + threadIdx.x;
    int e0 = t * 8;
    int p0 = e0 & (P - 1), c = e0 >> 12;
    half8 vg, vc;
    #pragma unroll
    for (int u = 0; u < 8; ++u) {
        float m = mask[p0 + u];
        vg[u] = (_Float16)(input[e0 + u] * m);
        vc[u] = (_Float16)(style[(c << 12) + idx[p0 + u]] * m);
    }
    *(half8*)(fg + e0) = vg;
    *(half8*)(fc + e0) = vc;
}

// ---------------- gram diff partials: part[z] = (fg fg^T - fc fc^T) over K-chunk z*256 ----------------
__global__ __launch_bounds__(256) void k_gram(const _Float16* __restrict__ fg,
                                              const _Float16* __restrict__ fc,
                                              float* __restrict__ part) {
    const int z = blockIdx.z;
    const int p0 = z * 256;
    const int wave = threadIdx.x >> 6, lane = threadIdx.x & 63;
    const int wr = wave >> 1, wc = wave & 1, quad = lane >> 4, l15 = lane & 15;
    const int a0 = blockIdx.y * 128 + wr * 64, b0 = blockIdx.x * 128 + wc * 64;

    f32x4 accg[4][4] = {};
    f32x4 accc[4][4] = {};
    for (int ks = 0; ks < 256; ks += 32) {
        int kbase = p0 + ks + quad * 8;
        half8 af[4], bf[4];
        #pragma unroll
        for (int mi = 0; mi < 4; ++mi) af[mi] = *(const half8*)(fg + (size_t)(a0 + mi * 16 + l15) * P + kbase);
        #pragma unroll
        for (int ni = 0; ni < 4; ++ni) bf[ni] = *(const half8*)(fg + (size_t)(b0 + ni * 16 + l15) * P + kbase);
        #pragma unroll
        for (int mi = 0; mi < 4; ++mi)
            #pragma unroll
            for (int ni = 0; ni < 4; ++ni)
                accg[mi][ni] = __builtin_amdgcn_mfma_f32_16x16x32_f16(af[mi], bf[ni], accg[mi][ni], 0, 0, 0);
        #pragma unroll
        for (int mi = 0; mi < 4; ++mi) af[mi] = *(const half8*)(fc + (size_t)(a0 + mi * 16 + l15) * P + kbase);
        #pragma unroll
        for (int ni = 0; ni < 4; ++ni) bf[ni] = *(const half8*)(fc + (size_t)(b0 + ni * 16 + l15) * P + kbase);
        #pragma unroll
        for (int mi = 0; mi < 4; ++mi)
            #pragma unroll
            for (int ni = 0; ni < 4; ++ni)
                accc[mi][ni] = __builtin_amdgcn_mfma_f32_16x16x32_f16(af[mi], bf[ni], accc[mi][ni], 0, 0, 0);
    }
    #pragma unroll
    for (int mi = 0; mi < 4; ++mi)
        #pragma unroll
        for (int ni = 0; ni < 4; ++ni)
            #pragma unroll
            for (int r = 0; r < 4; ++r)
                part[(size_t)z * CC + (size_t)(a0 + mi * 16 + quad * 4 + r) * C + b0 + ni * 16 + l15]
                    = accg[mi][ni][r] - accc[mi][ni][r];
}

// ---------------- loss: (sum_z part)^2 reduced; last block writes final scalar ----------------
__global__ void k_loss(const float* __restrict__ part, float* __restrict__ acc,
                       unsigned* __restrict__ cnt, const float* __restrict__ msum,
                       float* __restrict__ out) {
    int e = blockIdx.x * 256 + threadIdx.x;
    float d = 0.f;
    #pragma unroll
    for (int z = 0; z < 16; ++z) d += part[(size_t)z * CC + e];
    __shared__ float red[256];
    red[threadIdx.x] = d * d;
    __syncthreads();
    for (int t = 128; t > 0; t >>= 1) {
        if (threadIdx.x < t) red[threadIdx.x] += red[threadIdx.x + t];
        __syncthreads();
    }
    if (threadIdx.x == 0) {
        atomicAdd(acc, red[0]);
        __threadfence();
        unsigned old = atomicAdd(cnt, 1);
        if (old == 1023) {
            float a = __hip_atomic_load(acc, __ATOMIC_RELAXED, __HIP_MEMORY_SCOPE_AGENT);
            float m = msum[0];
            out[0] = a * 100.0f / (m * m * 262144.0f);
        }
    }
}

extern "C" void kernel_launch(void* const* d_in, const int* in_sizes, int n_in,
                              void* d_out, int out_size, void* d_ws, size_t ws_size,
                              hipStream_t stream) {
    (void)in_sizes; (void)n_in; (void)out_size; (void)ws_size;
    const float* content = (const float*)d_in[0];
    const float* style   = (const float*)d_in[1];
    const float* input   = (const float*)d_in[2];
    const float* mask    = (const float*)d_in[3];

    char* ws = (char*)d_ws;
    _Float16* D0h  = (_Float16*)ws;                        // 32 MB (dead after k_argmax)
    float*    part = (float*)ws;                           // 16 MB (overlays D0h)
    _Float16* Ah   = (_Float16*)(ws + (32u << 20));        // 4 MB
    _Float16* Bh   = (_Float16*)(ws + (36u << 20));        // 4 MB
    _Float16* fg_h = (_Float16*)(ws + (40u << 20));        // 4 MB
    _Float16* fc_h = (_Float16*)(ws + (44u << 20));        // 4 MB
    float*    small = (float*)(ws + (48u << 20));
    float*    sqn_s  = small;              // 4096
    float*    inv_sn = small + 4096;       // 4096
    float*    msum   = small + 8192;
    float*    acc    = small + 8193;
    unsigned* cntp   = (unsigned*)(small + 8194);
    unsigned* cntl   = (unsigned*)(small + 8195);
    int*      idx    = (int*)(small + 8196);
    float* out = (float*)d_out;

    k_init  <<<16, 256, 0, stream>>>(small);
    k_prep  <<<512, 256, 0, stream>>>(content, style, mask, Ah, Bh, sqn_s, inv_sn, msum, cntp);
    k_gemm16<<<dim3(32, 32), 256, 0, stream>>>(Ah, Bh, D0h);
    k_argmax<<<1024, 256, 0, stream>>>(D0h, inv_sn, idx);
    k_build <<<1024, 256, 0, stream>>>(style, input, mask, idx, fc_h, fg_h);
    k_gram  <<<dim3(4, 4, 16), 256, 0, stream>>>(fg_h, fc_h, part);
    k_loss  <<<1024, 256, 0, stream>>>(part, acc, cntl, msum, out);
}

// Round 5
// 197.773 us; speedup vs baseline: 1.3117x; 1.3117x over previous
//
#include <hip/hip_runtime.h>

static constexpr int C  = 512;
static constexpr int P  = 4096;    // H*W
static constexpr int CC = 262144;  // 512*512

typedef _Float16 half8  __attribute__((ext_vector_type(8)));
typedef _Float16 half2v __attribute__((ext_vector_type(2)));
typedef float    f32x4  __attribute__((ext_vector_type(4)));

__device__ __forceinline__ int refl(int q) { return q < 0 ? 1 : (q > 63 ? 62 : q); }

__device__ __forceinline__ void g2l16(const void* g, const void* l) {
    __builtin_amdgcn_global_load_lds((const __attribute__((address_space(1))) unsigned int*)g,
                                     (__attribute__((address_space(3))) unsigned int*)l, 16, 0, 0);
}

// ---------------- zero small scratch: sqn_s (4096) + acc ----------------
__global__ void k_init(float* __restrict__ small) {
    int e = blockIdx.x * 256 + threadIdx.x;
    if (e < 4096) small[e] = 0.0f;          // sqn_s
    if (e == 0) small[8193] = 0.0f;         // acc
}

// ---------------- transpose fp32 [c][p] -> fp16 [p][c]; style squared-norm ----------------
// NOTE (r4 post-mortem): NO __threadfence / last-block fusion here — device-scope
// fence in every block cost ~50 us aggregate; a separate launch is cheaper.
__global__ __launch_bounds__(256) void k_prep(const float* __restrict__ content, const float* __restrict__ style,
                                              _Float16* __restrict__ Ah, _Float16* __restrict__ Bh,
                                              float* __restrict__ sqn_s) {
    __shared__ float T[64][65];
    const int p0 = (blockIdx.x & 63) * 64, c0 = (blockIdx.x >> 6) * 64;
    const int pl = threadIdx.x & 63, cq = threadIdx.x >> 6;   // read role
    const int cl2 = threadIdx.x & 63, pq = threadIdx.x >> 6;  // write role

    // content (c_norm dropped from argmax: constant over j)
    #pragma unroll
    for (int r = 0; r < 16; ++r) {
        int cl = cq + r * 4;
        T[cl][pl] = content[(size_t)(c0 + cl) * P + p0 + pl];
    }
    __syncthreads();
    #pragma unroll
    for (int r = 0; r < 16; ++r) {
        int pl2 = pq + r * 4;
        Ah[(size_t)(p0 + pl2) * C + c0 + cl2] = (_Float16)T[cl2][pl2];
    }
    __syncthreads();

    // style
    float sq = 0.f;
    #pragma unroll
    for (int r = 0; r < 16; ++r) {
        int cl = cq + r * 4;
        float v = style[(size_t)(c0 + cl) * P + p0 + pl];
        T[cl][pl] = v;
        sq += v * v;
    }
    atomicAdd(&sqn_s[p0 + pl], sq);
    __syncthreads();
    #pragma unroll
    for (int r = 0; r < 16; ++r) {
        int pl2 = pq + r * 4;
        Bh[(size_t)(p0 + pl2) * C + c0 + cl2] = (_Float16)T[cl2][pl2];
    }
}

// ---------------- 3x3 reflect box-sum -> 1/patch_norm; block 0 also reduces mask sum ----------------
__global__ void k_pnorm(const float* __restrict__ sqn_s, const float* __restrict__ mask,
                        float* __restrict__ inv_sn, float* __restrict__ msum) {
    int p = blockIdx.x * 256 + threadIdx.x;
    int i = p >> 6, j = p & 63;
    float s2 = 0.f;
    #pragma unroll
    for (int dh = -1; dh <= 1; ++dh) {
        int ih = refl(i + dh);
        #pragma unroll
        for (int dw = -1; dw <= 1; ++dw)
            s2 += sqn_s[ih * 64 + refl(j + dw)];
    }
    inv_sn[p] = 1.0f / sqrtf(s2);

    if (blockIdx.x == 0) {
        __shared__ float red[256];
        float s = 0.f;
        for (int e = threadIdx.x; e < P; e += 256) s += mask[e];
        red[threadIdx.x] = s;
        __syncthreads();
        for (int t = 128; t > 0; t >>= 1) {
            if (threadIdx.x < t) red[threadIdx.x] += red[threadIdx.x + t];
            __syncthreads();
        }
        if (threadIdx.x == 0) msum[0] = red[0];
    }
}

// ---------------- D0 = Ah * Bh^T (4096x4096, K=512), fp16 MFMA, BK=64 m97-style ----------------
__global__ __launch_bounds__(256) void k_gemm16(const _Float16* __restrict__ Ah,
                                                const _Float16* __restrict__ Bh,
                                                _Float16* __restrict__ D0h) {
    __shared__ _Float16 As[128 * 64];
    __shared__ _Float16 Bs[128 * 64];
    const int tid = threadIdx.x;
    const int wave = tid >> 6, lane = tid & 63;
    const int wr = wave >> 1, wc = wave & 1;
    const int quad = lane >> 4, l15 = lane & 15;
    const int i0 = blockIdx.y * 128, j0 = blockIdx.x * 128;

    int mloc[4], goff[4];
    #pragma unroll
    for (int c2 = 0; c2 < 4; ++c2) {
        int m = wave * 32 + c2 * 8 + (lane >> 3);
        mloc[c2] = m;
        goff[c2] = ((lane & 7) ^ (m & 7)) * 8;
    }

    int aoff[4][2], boff[4][2];
    #pragma unroll
    for (int mi = 0; mi < 4; ++mi) {
        int m = wr * 64 + mi * 16 + l15;
        int n = wc * 64 + mi * 16 + l15;
        #pragma unroll
        for (int kh = 0; kh < 2; ++kh) {
            aoff[mi][kh] = m * 64 + ((quad + kh * 4) ^ (m & 7)) * 8;
            boff[mi][kh] = n * 64 + ((quad + kh * 4) ^ (n & 7)) * 8;
        }
    }

    f32x4 acc[4][4] = {};

    for (int kk = 0; kk < C; kk += 64) {
        __syncthreads();
        #pragma unroll
        for (int c2 = 0; c2 < 4; ++c2) {
            g2l16(Ah + (size_t)(i0 + mloc[c2]) * C + kk + goff[c2], As + (wave * 32 + c2 * 8) * 64);
            g2l16(Bh + (size_t)(j0 + mloc[c2]) * C + kk + goff[c2], Bs + (wave * 32 + c2 * 8) * 64);
        }
        __syncthreads();
        half8 af[2][4], bf[2][4];
        #pragma unroll
        for (int kh = 0; kh < 2; ++kh)
            #pragma unroll
            for (int mi = 0; mi < 4; ++mi) {
                af[kh][mi] = *(const half8*)(As + aoff[mi][kh]);
                bf[kh][mi] = *(const half8*)(Bs + boff[mi][kh]);
            }
        #pragma unroll
        for (int kh = 0; kh < 2; ++kh)
            #pragma unroll
            for (int mi = 0; mi < 4; ++mi)
                #pragma unroll
                for (int ni = 0; ni < 4; ++ni)
                    acc[mi][ni] = __builtin_amdgcn_mfma_f32_16x16x32_f16(af[kh][mi], bf[kh][ni], acc[mi][ni], 0, 0, 0);
    }

    #pragma unroll
    for (int mi = 0; mi < 4; ++mi) {
        int row = i0 + wr * 64 + mi * 16 + quad * 4;
        #pragma unroll
        for (int ni = 0; ni < 4; ++ni) {
            int col = j0 + wc * 64 + ni * 16 + l15;
            #pragma unroll
            for (int r = 0; r < 4; ++r)
                D0h[(size_t)(row + r) * P + col] = (_Float16)acc[mi][ni][r];
        }
    }
}

// ---------------- 9-shift score + argmax, 2x2 i-tile per block (16-row union vs 36) ----------------
__global__ __launch_bounds__(256) void k_argmax(const _Float16* __restrict__ D0h,
                                                const float* __restrict__ inv_sn,
                                                int* __restrict__ idxOut) {
    const int T = blockIdx.x;                 // 1024 tiles
    const int ih0 = (T >> 5) * 2, iw0 = (T & 31) * 2;
    const int wave = threadIdx.x >> 6, l = threadIdx.x & 63, l15 = l & 15;

    int rh[4], rw[4];
    rh[0] = refl(ih0 - 1); rh[1] = ih0; rh[2] = ih0 + 1; rh[3] = refl(ih0 + 2);
    rw[0] = refl(iw0 - 1); rw[1] = iw0; rw[2] = iw0 + 1; rw[3] = refl(iw0 + 2);
    int rb[3][2][4];
    #pragma unroll
    for (int d = 0; d < 3; ++d)
        #pragma unroll
        for (int di = 0; di < 2; ++di)
            #pragma unroll
            for (int k = 0; k < 4; ++k)
                rb[d][di][k] = (rh[di + d] * 64 + rw[k]) * P;

    float best[2][2] = {{-1e30f, -1e30f}, {-1e30f, -1e30f}};
    int   bidx[2][2] = {{0, 0}, {0, 0}};

    #pragma unroll
    for (int s = 0; s < 4; ++s) {
        const int ws = wave * 4 + s;
        const int j0 = ws * 256 + l * 4;
        const int jh = j0 >> 6;
        const int jw0 = l15 * 4;
        const int rs0 = (jh == 0) ? 1 : jh - 1;
        const int rs2 = (jh == 63) ? 62 : jh + 1;
        const int cb[3] = { rs0 * 64 + jw0, jh * 64 + jw0, rs2 * 64 + jw0 };

        float f[2][2][4] = {};
        #pragma unroll
        for (int d = 0; d < 3; ++d) {
            #pragma unroll
            for (int di = 0; di < 2; ++di) {
                uint2 u[4];
                #pragma unroll
                for (int k = 0; k < 4; ++k)
                    u[k] = *(const uint2*)(D0h + rb[d][di][k] + cb[d]);
                #pragma unroll
                for (int dj = 0; dj < 2; ++dj) {
                    const uint2 A = u[dj], Bc = u[dj + 1], Cc = u[dj + 2];
                    unsigned prev_hi = (unsigned)__shfl((int)A.y, l - 1);
                    unsigned next_lo = (unsigned)__shfl((int)Cc.x, l + 1);
                    unsigned left16  = ((l15 == 0) ? A.x : prev_hi) >> 16;
                    unsigned right16 = ((l15 == 15) ? Cc.y : next_lo) & 0xffffu;
                    unsigned wl0 = left16 | (A.x << 16);
                    unsigned wl1 = (A.x >> 16) | (A.y << 16);
                    unsigned wr0 = (Cc.x >> 16) | (Cc.y << 16);
                    unsigned wr1 = (Cc.y >> 16) | (right16 << 16);
                    half2v a0 = __builtin_bit_cast(half2v, wl0), a1 = __builtin_bit_cast(half2v, wl1);
                    half2v b0 = __builtin_bit_cast(half2v, Bc.x), b1 = __builtin_bit_cast(half2v, Bc.y);
                    half2v c0 = __builtin_bit_cast(half2v, wr0), c1 = __builtin_bit_cast(half2v, wr1);
                    f[di][dj][0] += (float)a0[0] + (float)b0[0] + (float)c0[0];
                    f[di][dj][1] += (float)a0[1] + (float)b0[1] + (float)c0[1];
                    f[di][dj][2] += (float)a1[0] + (float)b1[0] + (float)c1[0];
                    f[di][dj][3] += (float)a1[1] + (float)b1[1] + (float)c1[1];
                }
            }
        }
        const float4 is = *(const float4*)(inv_sn + j0);
        #pragma unroll
        for (int di = 0; di < 2; ++di)
            #pragma unroll
            for (int dj = 0; dj < 2; ++dj) {
                float v0 = f[di][dj][0] * is.x, v1 = f[di][dj][1] * is.y;
                float v2 = f[di][dj][2] * is.z, v3 = f[di][dj][3] * is.w;
                if (v0 > best[di][dj]) { best[di][dj] = v0; bidx[di][dj] = j0; }
                if (v1 > best[di][dj]) { best[di][dj] = v1; bidx[di][dj] = j0 + 1; }
                if (v2 > best[di][dj]) { best[di][dj] = v2; bidx[di][dj] = j0 + 2; }
                if (v3 > best[di][dj]) { best[di][dj] = v3; bidx[di][dj] = j0 + 3; }
            }
    }

    __shared__ float bv[256];
    __shared__ int   bi[256];
    #pragma unroll
    for (int di = 0; di < 2; ++di)
        #pragma unroll
        for (int dj = 0; dj < 2; ++dj) {
            __syncthreads();
            bv[threadIdx.x] = best[di][dj];
            bi[threadIdx.x] = bidx[di][dj];
            __syncthreads();
            for (int t = 128; t > 0; t >>= 1) {
                if (threadIdx.x < t) {
                    float ov = bv[threadIdx.x + t];
                    int   oi = bi[threadIdx.x + t];
                    if (ov > bv[threadIdx.x] || (ov == bv[threadIdx.x] && oi < bi[threadIdx.x])) {
                        bv[threadIdx.x] = ov;
                        bi[threadIdx.x] = oi;
                    }
                }
                __syncthreads();
            }
            if (threadIdx.x == 0) idxOut[(ih0 + di) * 64 + iw0 + dj] = bi[0];
        }
}

// ---------------- build masked fp16 matrices ----------------
__global__ void k_build(const float* __restrict__ style, const float* __restrict__ input,
                        const float* __restrict__ mask, const int* __restrict__ idx,
                        _Float16* __restrict__ fc, _Float16* __restrict__ fg) {
    int t = blockIdx.x * 256 + threadIdx.x;
    int e0 = t * 8;
    int p0 = e0 & (P - 1), c = e0 >> 12;
    half8 vg, vc;
    #pragma unroll
    for (int u = 0; u < 8; ++u) {
        float m = mask[p0 + u];
        vg[u] = (_Float16)(input[e0 + u] * m);
        vc[u] = (_Float16)(style[(c << 12) + idx[p0 + u]] * m);
    }
    *(half8*)(fg + e0) = vg;
    *(half8*)(fc + e0) = vc;
}

// ---------------- gram diff partials: part[z] = (fg fg^T - fc fc^T) over K-chunk z*256 ----------------
__global__ __launch_bounds__(256) void k_gram(const _Float16* __restrict__ fg,
                                              const _Float16* __restrict__ fc,
                                              float* __restrict__ part) {
    const int z = blockIdx.z;
    const int p0 = z * 256;
    const int wave = threadIdx.x >> 6, lane = threadIdx.x & 63;
    const int wr = wave >> 1, wc = wave & 1, quad = lane >> 4, l15 = lane & 15;
    const int a0 = blockIdx.y * 128 + wr * 64, b0 = blockIdx.x * 128 + wc * 64;

    f32x4 accg[4][4] = {};
    f32x4 accc[4][4] = {};
    for (int ks = 0; ks < 256; ks += 32) {
        int kbase = p0 + ks + quad * 8;
        half8 af[4], bf[4];
        #pragma unroll
        for (int mi = 0; mi < 4; ++mi) af[mi] = *(const half8*)(fg + (size_t)(a0 + mi * 16 + l15) * P + kbase);
        #pragma unroll
        for (int ni = 0; ni < 4; ++ni) bf[ni] = *(const half8*)(fg + (size_t)(b0 + ni * 16 + l15) * P + kbase);
        #pragma unroll
        for (int mi = 0; mi < 4; ++mi)
            #pragma unroll
            for (int ni = 0; ni < 4; ++ni)
                accg[mi][ni] = __builtin_amdgcn_mfma_f32_16x16x32_f16(af[mi], bf[ni], accg[mi][ni], 0, 0, 0);
        #pragma unroll
        for (int mi = 0; mi < 4; ++mi) af[mi] = *(const half8*)(fc + (size_t)(a0 + mi * 16 + l15) * P + kbase);
        #pragma unroll
        for (int ni = 0; ni < 4; ++ni) bf[ni] = *(const half8*)(fc + (size_t)(b0 + ni * 16 + l15) * P + kbase);
        #pragma unroll
        for (int mi = 0; mi < 4; ++mi)
            #pragma unroll
            for (int ni = 0; ni < 4; ++ni)
                accc[mi][ni] = __builtin_amdgcn_mfma_f32_16x16x32_f16(af[mi], bf[ni], accc[mi][ni], 0, 0, 0);
    }
    #pragma unroll
    for (int mi = 0; mi < 4; ++mi)
        #pragma unroll
        for (int ni = 0; ni < 4; ++ni)
            #pragma unroll
            for (int r = 0; r < 4; ++r)
                part[(size_t)z * CC + (size_t)(a0 + mi * 16 + quad * 4 + r) * C + b0 + ni * 16 + l15]
                    = accg[mi][ni][r] - accc[mi][ni][r];
}

// ---------------- loss: (sum_z part)^2 reduced ----------------
__global__ void k_loss(const float* __restrict__ part, float* __restrict__ acc) {
    int e = blockIdx.x * 256 + threadIdx.x;
    float d = 0.f;
    #pragma unroll
    for (int z = 0; z < 16; ++z) d += part[(size_t)z * CC + e];
    __shared__ float red[256];
    red[threadIdx.x] = d * d;
    __syncthreads();
    for (int t = 128; t > 0; t >>= 1) {
        if (threadIdx.x < t) red[threadIdx.x] += red[threadIdx.x + t];
        __syncthreads();
    }
    if (threadIdx.x == 0) atomicAdd(acc, red[0]);
}

__global__ void k_final(const float* __restrict__ msum, const float* __restrict__ acc,
                        float* __restrict__ out) {
    float m = msum[0];
    out[0] = acc[0] * 100.0f / (m * m * 262144.0f);
}

extern "C" void kernel_launch(void* const* d_in, const int* in_sizes, int n_in,
                              void* d_out, int out_size, void* d_ws, size_t ws_size,
                              hipStream_t stream) {
    (void)in_sizes; (void)n_in; (void)out_size; (void)ws_size;
    const float* content = (const float*)d_in[0];
    const float* style   = (const float*)d_in[1];
    const float* input   = (const float*)d_in[2];
    const float* mask    = (const float*)d_in[3];

    char* ws = (char*)d_ws;
    _Float16* D0h  = (_Float16*)ws;                        // 32 MB (dead after k_argmax)
    float*    part = (float*)ws;                           // 16 MB (overlays D0h)
    _Float16* Ah   = (_Float16*)(ws + (32u << 20));        // 4 MB
    _Float16* Bh   = (_Float16*)(ws + (36u << 20));        // 4 MB
    _Float16* fg_h = (_Float16*)(ws + (40u << 20));        // 4 MB
    _Float16* fc_h = (_Float16*)(ws + (44u << 20));        // 4 MB
    float*    small = (float*)(ws + (48u << 20));
    float* sqn_s  = small;            // 4096
    float* inv_sn = small + 4096;     // 4096
    float* msum   = small + 8192;
    float* acc    = small + 8193;
    int*   idx    = (int*)(small + 8194);
    float* out = (float*)d_out;

    k_init  <<<16, 256, 0, stream>>>(small);
    k_prep  <<<512, 256, 0, stream>>>(content, style, Ah, Bh, sqn_s);
    k_pnorm <<<16, 256, 0, stream>>>(sqn_s, mask, inv_sn, msum);
    k_gemm16<<<dim3(32, 32), 256, 0, stream>>>(Ah, Bh, D0h);
    k_argmax<<<1024, 256, 0, stream>>>(D0h, inv_sn, idx);
    k_build <<<1024, 256, 0, stream>>>(style, input, mask, idx, fc_h, fg_h);
    k_gram  <<<dim3(4, 4, 16), 256, 0, stream>>>(fg_h, fc_h, part);
    k_loss  <<<1024, 256, 0, stream>>>(part, acc);
    k_final <<<1, 1, 0, stream>>>(msum, acc, out);
}

// Round 6
// 173.143 us; speedup vs baseline: 1.4982x; 1.1423x over previous
//
#include <hip/hip_runtime.h>

static constexpr int C  = 512;
static constexpr int P  = 4096;    // H*W
static constexpr int CC = 262144;  // 512*512

typedef _Float16 half8  __attribute__((ext_vector_type(8)));
typedef _Float16 half2v __attribute__((ext_vector_type(2)));
typedef float    f32x4  __attribute__((ext_vector_type(4)));

__device__ __forceinline__ int refl(int q) { return q < 0 ? 1 : (q > 63 ? 62 : q); }

__device__ __forceinline__ void g2l16(const void* g, const void* l) {
    __builtin_amdgcn_global_load_lds((const __attribute__((address_space(1))) unsigned int*)g,
                                     (__attribute__((address_space(3))) unsigned int*)l, 16, 0, 0);
}

// ---------------- zero small scratch: sqn_s (4096) + acc ----------------
__global__ void k_init(float* __restrict__ small) {
    int e = blockIdx.x * 256 + threadIdx.x;
    if (e < 4096) small[e] = 0.0f;          // sqn_s
    if (e == 0) small[8193] = 0.0f;         // acc
}

// ---------------- transpose fp32 [c][p] -> fp16 [p][c]; style squared-norm ----------------
// NOTE (r4 post-mortem): NO __threadfence / last-block fusion — device-scope fence
// in every block cost ~50 us aggregate; a separate launch is cheaper.
__global__ __launch_bounds__(256) void k_prep(const float* __restrict__ content, const float* __restrict__ style,
                                              _Float16* __restrict__ Ah, _Float16* __restrict__ Bh,
                                              float* __restrict__ sqn_s) {
    __shared__ float T[64][65];
    const int p0 = (blockIdx.x & 63) * 64, c0 = (blockIdx.x >> 6) * 64;
    const int pl = threadIdx.x & 63, cq = threadIdx.x >> 6;   // read role
    const int cl2 = threadIdx.x & 63, pq = threadIdx.x >> 6;  // write role

    #pragma unroll
    for (int r = 0; r < 16; ++r) {
        int cl = cq + r * 4;
        T[cl][pl] = content[(size_t)(c0 + cl) * P + p0 + pl];
    }
    __syncthreads();
    #pragma unroll
    for (int r = 0; r < 16; ++r) {
        int pl2 = pq + r * 4;
        Ah[(size_t)(p0 + pl2) * C + c0 + cl2] = (_Float16)T[cl2][pl2];
    }
    __syncthreads();

    float sq = 0.f;
    #pragma unroll
    for (int r = 0; r < 16; ++r) {
        int cl = cq + r * 4;
        float v = style[(size_t)(c0 + cl) * P + p0 + pl];
        T[cl][pl] = v;
        sq += v * v;
    }
    atomicAdd(&sqn_s[p0 + pl], sq);
    __syncthreads();
    #pragma unroll
    for (int r = 0; r < 16; ++r) {
        int pl2 = pq + r * 4;
        Bh[(size_t)(p0 + pl2) * C + c0 + cl2] = (_Float16)T[cl2][pl2];
    }
}

// ---------------- 3x3 reflect box-sum -> 1/patch_norm; block 0 also reduces mask sum ----------------
__global__ void k_pnorm(const float* __restrict__ sqn_s, const float* __restrict__ mask,
                        float* __restrict__ inv_sn, float* __restrict__ msum) {
    int p = blockIdx.x * 256 + threadIdx.x;
    int i = p >> 6, j = p & 63;
    float s2 = 0.f;
    #pragma unroll
    for (int dh = -1; dh <= 1; ++dh) {
        int ih = refl(i + dh);
        #pragma unroll
        for (int dw = -1; dw <= 1; ++dw)
            s2 += sqn_s[ih * 64 + refl(j + dw)];
    }
    inv_sn[p] = 1.0f / sqrtf(s2);

    if (blockIdx.x == 0) {
        __shared__ float red[256];
        float s = 0.f;
        for (int e = threadIdx.x; e < P; e += 256) s += mask[e];
        red[threadIdx.x] = s;
        __syncthreads();
        for (int t = 128; t > 0; t >>= 1) {
            if (threadIdx.x < t) red[threadIdx.x] += red[threadIdx.x + t];
            __syncthreads();
        }
        if (threadIdx.x == 0) msum[0] = red[0];
    }
}

// ---------------- D0 GEMM + fused w-diagonal 3-sum epilogue -> E ----------------
// E[a][b] = sum_dw D0[ah*64+refl(aw+dw)][bh*64+refl(bw+dw)]; the +-1 w-shifts stay
// inside 64-aligned blocks, so a 128x128 tile is self-contained. LDS staging buffer
// (32 KB) is reused for the fp16 acc tile (stride 130 halfs: row stride 65 dwords,
// 65%32=1 -> consecutive rows hit consecutive banks).
__global__ __launch_bounds__(256) void k_gemm16(const _Float16* __restrict__ Ah,
                                                const _Float16* __restrict__ Bh,
                                                _Float16* __restrict__ Eo) {
    __shared__ _Float16 SH[16640];             // max(As+Bs = 16384, tile 128*130 = 16640)
    _Float16* As = SH;
    _Float16* Bs = SH + 8192;
    const int tid = threadIdx.x;
    const int wave = tid >> 6, lane = tid & 63;
    const int wr = wave >> 1, wc = wave & 1;
    const int quad = lane >> 4, l15 = lane & 15;
    const int i0 = blockIdx.y * 128, j0 = blockIdx.x * 128;

    int mloc[4], goff[4];
    #pragma unroll
    for (int c2 = 0; c2 < 4; ++c2) {
        int m = wave * 32 + c2 * 8 + (lane >> 3);
        mloc[c2] = m;
        goff[c2] = ((lane & 7) ^ (m & 7)) * 8;
    }

    int aoff[4][2], boff[4][2];
    #pragma unroll
    for (int mi = 0; mi < 4; ++mi) {
        int m = wr * 64 + mi * 16 + l15;
        int n = wc * 64 + mi * 16 + l15;
        #pragma unroll
        for (int kh = 0; kh < 2; ++kh) {
            aoff[mi][kh] = m * 64 + ((quad + kh * 4) ^ (m & 7)) * 8;
            boff[mi][kh] = n * 64 + ((quad + kh * 4) ^ (n & 7)) * 8;
        }
    }

    f32x4 acc[4][4] = {};

    for (int kk = 0; kk < C; kk += 64) {
        __syncthreads();
        #pragma unroll
        for (int c2 = 0; c2 < 4; ++c2) {
            g2l16(Ah + (size_t)(i0 + mloc[c2]) * C + kk + goff[c2], As + (wave * 32 + c2 * 8) * 64);
            g2l16(Bh + (size_t)(j0 + mloc[c2]) * C + kk + goff[c2], Bs + (wave * 32 + c2 * 8) * 64);
        }
        __syncthreads();
        half8 af[2][4], bf[2][4];
        #pragma unroll
        for (int kh = 0; kh < 2; ++kh)
            #pragma unroll
            for (int mi = 0; mi < 4; ++mi) {
                af[kh][mi] = *(const half8*)(As + aoff[mi][kh]);
                bf[kh][mi] = *(const half8*)(Bs + boff[mi][kh]);
            }
        #pragma unroll
        for (int kh = 0; kh < 2; ++kh)
            #pragma unroll
            for (int mi = 0; mi < 4; ++mi)
                #pragma unroll
                for (int ni = 0; ni < 4; ++ni)
                    acc[mi][ni] = __builtin_amdgcn_mfma_f32_16x16x32_f16(af[kh][mi], bf[kh][ni], acc[mi][ni], 0, 0, 0);
    }

    // ---- epilogue: acc -> LDS tile (fp16), then E = w-diagonal 3-sum -> global ----
    __syncthreads();   // all LDS reads of As/Bs done before overwrite
    #pragma unroll
    for (int mi = 0; mi < 4; ++mi) {
        int row = wr * 64 + mi * 16 + quad * 4;
        #pragma unroll
        for (int ni = 0; ni < 4; ++ni) {
            int col = wc * 64 + ni * 16 + l15;
            #pragma unroll
            for (int r = 0; r < 4; ++r)
                SH[(row + r) * 130 + col] = (_Float16)acc[mi][ni][r];
        }
    }
    __syncthreads();

    const int er  = tid >> 1;              // 0..127
    const int ec0 = (tid & 1) << 6;        // 0 or 64
    const int aw = er & 63;
    const int rm = (er & 64) | (aw == 0 ? 1 : aw - 1);
    const int rp = (er & 64) | (aw == 63 ? 62 : aw + 1);
    _Float16* outRow = Eo + (size_t)(i0 + er) * P + j0 + ec0;
    #pragma unroll
    for (int cc = 0; cc < 64; cc += 8) {
        half8 ev;
        #pragma unroll
        for (int u = 0; u < 8; ++u) {
            int c = ec0 + cc + u;
            int cw = c & 63;
            int cm = (c & 64) | (cw == 0 ? 1 : cw - 1);
            int cp = (c & 64) | (cw == 63 ? 62 : cw + 1);
            ev[u] = (_Float16)((float)SH[rm * 130 + cm] + (float)SH[er * 130 + c] + (float)SH[rp * 130 + cp]);
        }
        *(half8*)(outRow + cc) = ev;
    }
}

// ---------------- h-diagonal 3-sum + normalize + argmax: 3 aligned loads per 4-j, no shuffles ----------------
__global__ __launch_bounds__(256) void k_argmax(const _Float16* __restrict__ E,
                                                const float* __restrict__ inv_sn,
                                                int* __restrict__ idxOut) {
    const int i = blockIdx.x;
    const int ih = i >> 6, iw = i & 63;
    const int wave = threadIdx.x >> 6, l = threadIdx.x & 63, l15 = l & 15;
    size_t rb0 = (size_t)(refl(ih - 1) * 64 + iw) * P;
    size_t rb1 = (size_t)(ih * 64 + iw) * P;
    size_t rb2 = (size_t)(refl(ih + 1) * 64 + iw) * P;

    float best = -1e30f;
    int bidx = 0;
    #pragma unroll
    for (int s = 0; s < 4; ++s) {
        const int j0 = (wave * 4 + s) * 256 + l * 4;
        const int jh = j0 >> 6, jw0 = l15 * 4;
        const int cb0 = ((jh == 0) ? 1 : jh - 1) * 64 + jw0;
        const int cb1 = jh * 64 + jw0;
        const int cb2 = ((jh == 63) ? 62 : jh + 1) * 64 + jw0;
        uint2 u0 = *(const uint2*)(E + rb0 + cb0);
        uint2 u1 = *(const uint2*)(E + rb1 + cb1);
        uint2 u2 = *(const uint2*)(E + rb2 + cb2);
        half2v a0 = __builtin_bit_cast(half2v, u0.x), a1 = __builtin_bit_cast(half2v, u0.y);
        half2v b0 = __builtin_bit_cast(half2v, u1.x), b1 = __builtin_bit_cast(half2v, u1.y);
        half2v c0 = __builtin_bit_cast(half2v, u2.x), c1 = __builtin_bit_cast(half2v, u2.y);
        float f0 = (float)a0[0] + (float)b0[0] + (float)c0[0];
        float f1 = (float)a0[1] + (float)b0[1] + (float)c0[1];
        float f2 = (float)a1[0] + (float)b1[0] + (float)c1[0];
        float f3 = (float)a1[1] + (float)b1[1] + (float)c1[1];
        const float4 is = *(const float4*)(inv_sn + j0);
        float v0 = f0 * is.x, v1 = f1 * is.y, v2 = f2 * is.z, v3 = f3 * is.w;
        if (v0 > best) { best = v0; bidx = j0; }
        if (v1 > best) { best = v1; bidx = j0 + 1; }
        if (v2 > best) { best = v2; bidx = j0 + 2; }
        if (v3 > best) { best = v3; bidx = j0 + 3; }
    }

    __shared__ float bv[256];
    __shared__ int   bi[256];
    bv[threadIdx.x] = best;
    bi[threadIdx.x] = bidx;
    __syncthreads();
    for (int t = 128; t > 0; t >>= 1) {
        if (threadIdx.x < t) {
            float ov = bv[threadIdx.x + t];
            int   oi = bi[threadIdx.x + t];
            if (ov > bv[threadIdx.x] || (ov == bv[threadIdx.x] && oi < bi[threadIdx.x])) {
                bv[threadIdx.x] = ov;
                bi[threadIdx.x] = oi;
            }
        }
        __syncthreads();
    }
    if (threadIdx.x == 0) idxOut[i] = bi[0];
}

// ---------------- build masked fp16 matrices ----------------
__global__ void k_build(const float* __restrict__ style, const float* __restrict__ input,
                        const float* __restrict__ mask, const int* __restrict__ idx,
                        _Float16* __restrict__ fc, _Float16* __restrict__ fg) {
    int t = blockIdx.x * 256 + threadIdx.x;
    int e0 = t * 8;
    int p0 = e0 & (P - 1), c = e0 >> 12;
    half8 vg, vc;
    #pragma unroll
    for (int u = 0; u < 8; ++u) {
        float m = mask[p0 + u];
        vg[u] = (_Float16)(input[e0 + u] * m);
        vc[u] = (_Float16)(style[(c << 12) + idx[p0 + u]] * m);
    }
    *(half8*)(fg + e0) = vg;
    *(half8*)(fc + e0) = vc;
}

// ---------------- gram diff partials: part[z] = (fg fg^T - fc fc^T) over K-chunk z*256 ----------------
__global__ __launch_bounds__(256) void k_gram(const _Float16* __restrict__ fg,
                                              const _Float16* __restrict__ fc,
                                              float* __restrict__ part) {
    const int z = blockIdx.z;
    const int p0 = z * 256;
    const int wave = threadIdx.x >> 6, lane = threadIdx.x & 63;
    const int wr = wave >> 1, wc = wave & 1, quad = lane >> 4, l15 = lane & 15;
    const int a0 = blockIdx.y * 128 + wr * 64, b0 = blockIdx.x * 128 + wc * 64;

    f32x4 accg[4][4] = {};
    f32x4 accc[4][4] = {};
    for (int ks = 0; ks < 256; ks += 32) {
        int kbase = p0 + ks + quad * 8;
        half8 af[4], bf[4];
        #pragma unroll
        for (int mi = 0; mi < 4; ++mi) af[mi] = *(const half8*)(fg + (size_t)(a0 + mi * 16 + l15) * P + kbase);
        #pragma unroll
        for (int ni = 0; ni < 4; ++ni) bf[ni] = *(const half8*)(fg + (size_t)(b0 + ni * 16 + l15) * P + kbase);
        #pragma unroll
        for (int mi = 0; mi < 4; ++mi)
            #pragma unroll
            for (int ni = 0; ni < 4; ++ni)
                accg[mi][ni] = __builtin_amdgcn_mfma_f32_16x16x32_f16(af[mi], bf[ni], accg[mi][ni], 0, 0, 0);
        #pragma unroll
        for (int mi = 0; mi < 4; ++mi) af[mi] = *(const half8*)(fc + (size_t)(a0 + mi * 16 + l15) * P + kbase);
        #pragma unroll
        for (int ni = 0; ni < 4; ++ni) bf[ni] = *(const half8*)(fc + (size_t)(b0 + ni * 16 + l15) * P + kbase);
        #pragma unroll
        for (int mi = 0; mi < 4; ++mi)
            #pragma unroll
            for (int ni = 0; ni < 4; ++ni)
                accc[mi][ni] = __builtin_amdgcn_mfma_f32_16x16x32_f16(af[mi], bf[ni], accc[mi][ni], 0, 0, 0);
    }
    #pragma unroll
    for (int mi = 0; mi < 4; ++mi)
        #pragma unroll
        for (int ni = 0; ni < 4; ++ni)
            #pragma unroll
            for (int r = 0; r < 4; ++r)
                part[(size_t)z * CC + (size_t)(a0 + mi * 16 + quad * 4 + r) * C + b0 + ni * 16 + l15]
                    = accg[mi][ni][r] - accc[mi][ni][r];
}

// ---------------- loss: (sum_z part)^2 reduced ----------------
__global__ void k_loss(const float* __restrict__ part, float* __restrict__ acc) {
    int e = blockIdx.x * 256 + threadIdx.x;
    float d = 0.f;
    #pragma unroll
    for (int z = 0; z < 16; ++z) d += part[(size_t)z * CC + e];
    __shared__ float red[256];
    red[threadIdx.x] = d * d;
    __syncthreads();
    for (int t = 128; t > 0; t >>= 1) {
        if (threadIdx.x < t) red[threadIdx.x] += red[threadIdx.x + t];
        __syncthreads();
    }
    if (threadIdx.x == 0) atomicAdd(acc, red[0]);
}

__global__ void k_final(const float* __restrict__ msum, const float* __restrict__ acc,
                        float* __restrict__ out) {
    float m = msum[0];
    out[0] = acc[0] * 100.0f / (m * m * 262144.0f);
}

extern "C" void kernel_launch(void* const* d_in, const int* in_sizes, int n_in,
                              void* d_out, int out_size, void* d_ws, size_t ws_size,
                              hipStream_t stream) {
    (void)in_sizes; (void)n_in; (void)out_size; (void)ws_size;
    const float* content = (const float*)d_in[0];
    const float* style   = (const float*)d_in[1];
    const float* input   = (const float*)d_in[2];
    const float* mask    = (const float*)d_in[3];

    char* ws = (char*)d_ws;
    _Float16* Eb   = (_Float16*)ws;                        // 32 MB (dead after k_argmax)
    float*    part = (float*)ws;                           // 16 MB (overlays Eb)
    _Float16* Ah   = (_Float16*)(ws + (32u << 20));        // 4 MB
    _Float16* Bh   = (_Float16*)(ws + (36u << 20));        // 4 MB
    _Float16* fg_h = (_Float16*)(ws + (40u << 20));        // 4 MB
    _Float16* fc_h = (_Float16*)(ws + (44u << 20));        // 4 MB
    float*    small = (float*)(ws + (48u << 20));
    float* sqn_s  = small;            // 4096
    float* inv_sn = small + 4096;     // 4096
    float* msum   = small + 8192;
    float* acc    = small + 8193;
    int*   idx    = (int*)(small + 8194);
    float* out = (float*)d_out;

    k_init  <<<16, 256, 0, stream>>>(small);
    k_prep  <<<512, 256, 0, stream>>>(content, style, Ah, Bh, sqn_s);
    k_pnorm <<<16, 256, 0, stream>>>(sqn_s, mask, inv_sn, msum);
    k_gemm16<<<dim3(32, 32), 256, 0, stream>>>(Ah, Bh, Eb);
    k_argmax<<<4096, 256, 0, stream>>>(Eb, inv_sn, idx);
    k_build <<<1024, 256, 0, stream>>>(style, input, mask, idx, fc_h, fg_h);
    k_gram  <<<dim3(4, 4, 16), 256, 0, stream>>>(fg_h, fc_h, part);
    k_loss  <<<1024, 256, 0, stream>>>(part, acc);
    k_final <<<1, 1, 0, stream>>>(msum, acc, out);
}

// Round 7
// 155.436 us; speedup vs baseline: 1.6689x; 1.1139x over previous
//
#include <hip/hip_runtime.h>

static constexpr int C  = 512;
static constexpr int P  = 4096;    // H*W

typedef _Float16 half8  __attribute__((ext_vector_type(8)));
typedef _Float16 half2v __attribute__((ext_vector_type(2)));
typedef float    f32x4  __attribute__((ext_vector_type(4)));

__device__ __forceinline__ int refl(int q) { return q < 0 ? 1 : (q > 63 ? 62 : q); }

__device__ __forceinline__ void g2l16(const void* g, const void* l) {
    __builtin_amdgcn_global_load_lds((const __attribute__((address_space(1))) unsigned int*)g,
                                     (__attribute__((address_space(3))) unsigned int*)l, 16, 0, 0);
}

// ---------------- transpose fp32 [c][p] -> fp16 [p][c]; per-cblk style sq-norm partials ----------------
// No atomics (r7): LDS 4-way reduce -> plain store to sqn_part[cblk][p]. No zero-init needed.
__global__ __launch_bounds__(256) void k_prep(const float* __restrict__ content, const float* __restrict__ style,
                                              _Float16* __restrict__ Ah, _Float16* __restrict__ Bh,
                                              float* __restrict__ sqn_part) {
    __shared__ float T[64][65];
    __shared__ float R4[4][64];
    const int p0 = (blockIdx.x & 63) * 64, c0 = (blockIdx.x >> 6) * 64;
    const int pl = threadIdx.x & 63, cq = threadIdx.x >> 6;   // read role
    const int pv = threadIdx.x >> 3;                           // write role: p row 0..31 (+32)
    const int cv = (threadIdx.x & 7) * 8;                      // write role: c base

    // content
    #pragma unroll
    for (int r = 0; r < 16; ++r)
        T[cq + r * 4][pl] = content[(size_t)(c0 + cq + r * 4) * P + p0 + pl];
    __syncthreads();
    #pragma unroll
    for (int r = 0; r < 2; ++r) {
        int pl2 = pv + r * 32;
        half8 v;
        #pragma unroll
        for (int u = 0; u < 8; ++u) v[u] = (_Float16)T[cv + u][pl2];
        *(half8*)(Ah + (size_t)(p0 + pl2) * C + c0 + cv) = v;
    }
    __syncthreads();

    // style
    float sq = 0.f;
    #pragma unroll
    for (int r = 0; r < 16; ++r) {
        float v = style[(size_t)(c0 + cq + r * 4) * P + p0 + pl];
        T[cq + r * 4][pl] = v;
        sq += v * v;
    }
    R4[cq][pl] = sq;
    __syncthreads();
    if (cq == 0)
        sqn_part[(size_t)(blockIdx.x >> 6) * P + p0 + pl] = R4[0][pl] + R4[1][pl] + R4[2][pl] + R4[3][pl];
    #pragma unroll
    for (int r = 0; r < 2; ++r) {
        int pl2 = pv + r * 32;
        half8 v;
        #pragma unroll
        for (int u = 0; u < 8; ++u) v[u] = (_Float16)T[cv + u][pl2];
        *(half8*)(Bh + (size_t)(p0 + pl2) * C + c0 + cv) = v;
    }
}

// ---------------- 3x3 reflect box-sum of (sum of 8 partials) -> 1/patch_norm; block 0: mask sum ----------------
__global__ void k_pnorm(const float* __restrict__ sqn_part, const float* __restrict__ mask,
                        float* __restrict__ inv_sn, float* __restrict__ msum) {
    __shared__ float sqs[6][64];               // reflected ih rows b*4-1 .. b*4+4
    const int b = blockIdx.x;                  // 16 blocks, 4 ih rows each
    for (int e = threadIdx.x; e < 384; e += 256) {
        int rr = e >> 6, jw = e & 63;
        int gr = refl(b * 4 - 1 + rr);
        float s = 0.f;
        #pragma unroll
        for (int k = 0; k < 8; ++k) s += sqn_part[(size_t)k * P + gr * 64 + jw];
        sqs[rr][jw] = s;
    }
    __syncthreads();

    int p = b * 256 + threadIdx.x;
    int li = (threadIdx.x >> 6) + 1;           // slot of own ih (slot 0 = ih-1 of first row)
    int j = p & 63;
    float s2 = 0.f;
    #pragma unroll
    for (int dh = -1; dh <= 1; ++dh) {
        #pragma unroll
        for (int dw = -1; dw <= 1; ++dw)
            s2 += sqs[li + dh][refl(j + dw)];
    }
    inv_sn[p] = 1.0f / sqrtf(s2);

    if (b == 0) {
        __shared__ float red[256];
        float s = 0.f;
        for (int e = threadIdx.x; e < P; e += 256) s += mask[e];
        red[threadIdx.x] = s;
        __syncthreads();
        for (int t = 128; t > 0; t >>= 1) {
            if (threadIdx.x < t) red[threadIdx.x] += red[threadIdx.x + t];
            __syncthreads();
        }
        if (threadIdx.x == 0) msum[0] = red[0];
    }
}

// ---------------- D0 GEMM + fused w-diagonal 3-sum epilogue -> E (unchanged from r6) ----------------
__global__ __launch_bounds__(256) void k_gemm16(const _Float16* __restrict__ Ah,
                                                const _Float16* __restrict__ Bh,
                                                _Float16* __restrict__ Eo) {
    __shared__ _Float16 SH[16640];             // max(As+Bs = 16384, tile 128*130 = 16640)
    _Float16* As = SH;
    _Float16* Bs = SH + 8192;
    const int tid = threadIdx.x;
    const int wave = tid >> 6, lane = tid & 63;
    const int wr = wave >> 1, wc = wave & 1;
    const int quad = lane >> 4, l15 = lane & 15;
    const int i0 = blockIdx.y * 128, j0 = blockIdx.x * 128;

    int mloc[4], goff[4];
    #pragma unroll
    for (int c2 = 0; c2 < 4; ++c2) {
        int m = wave * 32 + c2 * 8 + (lane >> 3);
        mloc[c2] = m;
        goff[c2] = ((lane & 7) ^ (m & 7)) * 8;
    }

    int aoff[4][2], boff[4][2];
    #pragma unroll
    for (int mi = 0; mi < 4; ++mi) {
        int m = wr * 64 + mi * 16 + l15;
        int n = wc * 64 + mi * 16 + l15;
        #pragma unroll
        for (int kh = 0; kh < 2; ++kh) {
            aoff[mi][kh] = m * 64 + ((quad + kh * 4) ^ (m & 7)) * 8;
            boff[mi][kh] = n * 64 + ((quad + kh * 4) ^ (n & 7)) * 8;
        }
    }

    f32x4 acc[4][4] = {};

    for (int kk = 0; kk < C; kk += 64) {
        __syncthreads();
        #pragma unroll
        for (int c2 = 0; c2 < 4; ++c2) {
            g2l16(Ah + (size_t)(i0 + mloc[c2]) * C + kk + goff[c2], As + (wave * 32 + c2 * 8) * 64);
            g2l16(Bh + (size_t)(j0 + mloc[c2]) * C + kk + goff[c2], Bs + (wave * 32 + c2 * 8) * 64);
        }
        __syncthreads();
        half8 af[2][4], bf[2][4];
        #pragma unroll
        for (int kh = 0; kh < 2; ++kh)
            #pragma unroll
            for (int mi = 0; mi < 4; ++mi) {
                af[kh][mi] = *(const half8*)(As + aoff[mi][kh]);
                bf[kh][mi] = *(const half8*)(Bs + boff[mi][kh]);
            }
        #pragma unroll
        for (int kh = 0; kh < 2; ++kh)
            #pragma unroll
            for (int mi = 0; mi < 4; ++mi)
                #pragma unroll
                for (int ni = 0; ni < 4; ++ni)
                    acc[mi][ni] = __builtin_amdgcn_mfma_f32_16x16x32_f16(af[kh][mi], bf[kh][ni], acc[mi][ni], 0, 0, 0);
    }

    // epilogue: acc -> LDS fp16 tile (stride 130), then E = w-diagonal 3-sum -> global
    __syncthreads();
    #pragma unroll
    for (int mi = 0; mi < 4; ++mi) {
        int row = wr * 64 + mi * 16 + quad * 4;
        #pragma unroll
        for (int ni = 0; ni < 4; ++ni) {
            int col = wc * 64 + ni * 16 + l15;
            #pragma unroll
            for (int r = 0; r < 4; ++r)
                SH[(row + r) * 130 + col] = (_Float16)acc[mi][ni][r];
        }
    }
    __syncthreads();

    const int er  = tid >> 1;
    const int ec0 = (tid & 1) << 6;
    const int aw = er & 63;
    const int rm = (er & 64) | (aw == 0 ? 1 : aw - 1);
    const int rp = (er & 64) | (aw == 63 ? 62 : aw + 1);
    _Float16* outRow = Eo + (size_t)(i0 + er) * P + j0 + ec0;
    #pragma unroll
    for (int cc = 0; cc < 64; cc += 8) {
        half8 ev;
        #pragma unroll
        for (int u = 0; u < 8; ++u) {
            int c = ec0 + cc + u;
            int cw = c & 63;
            int cm = (c & 64) | (cw == 0 ? 1 : cw - 1);
            int cp = (c & 64) | (cw == 63 ? 62 : cw + 1);
            ev[u] = (_Float16)((float)SH[rm * 130 + cm] + (float)SH[er * 130 + c] + (float)SH[rp * 130 + cp]);
        }
        *(half8*)(outRow + cc) = ev;
    }
}

// ---------------- h-diagonal 3-sum + normalize + argmax (unchanged from r6) ----------------
__global__ __launch_bounds__(256) void k_argmax(const _Float16* __restrict__ E,
                                                const float* __restrict__ inv_sn,
                                                int* __restrict__ idxOut) {
    const int i = blockIdx.x;
    const int ih = i >> 6, iw = i & 63;
    const int wave = threadIdx.x >> 6, l = threadIdx.x & 63, l15 = l & 15;
    size_t rb0 = (size_t)(refl(ih - 1) * 64 + iw) * P;
    size_t rb1 = (size_t)(ih * 64 + iw) * P;
    size_t rb2 = (size_t)(refl(ih + 1) * 64 + iw) * P;

    float best = -1e30f;
    int bidx = 0;
    #pragma unroll
    for (int s = 0; s < 4; ++s) {
        const int j0 = (wave * 4 + s) * 256 + l * 4;
        const int jh = j0 >> 6, jw0 = l15 * 4;
        const int cb0 = ((jh == 0) ? 1 : jh - 1) * 64 + jw0;
        const int cb1 = jh * 64 + jw0;
        const int cb2 = ((jh == 63) ? 62 : jh + 1) * 64 + jw0;
        uint2 u0 = *(const uint2*)(E + rb0 + cb0);
        uint2 u1 = *(const uint2*)(E + rb1 + cb1);
        uint2 u2 = *(const uint2*)(E + rb2 + cb2);
        half2v a0 = __builtin_bit_cast(half2v, u0.x), a1 = __builtin_bit_cast(half2v, u0.y);
        half2v b0 = __builtin_bit_cast(half2v, u1.x), b1 = __builtin_bit_cast(half2v, u1.y);
        half2v c0 = __builtin_bit_cast(half2v, u2.x), c1 = __builtin_bit_cast(half2v, u2.y);
        float f0 = (float)a0[0] + (float)b0[0] + (float)c0[0];
        float f1 = (float)a0[1] + (float)b0[1] + (float)c0[1];
        float f2 = (float)a1[0] + (float)b1[0] + (float)c1[0];
        float f3 = (float)a1[1] + (float)b1[1] + (float)c1[1];
        const float4 is = *(const float4*)(inv_sn + j0);
        float v0 = f0 * is.x, v1 = f1 * is.y, v2 = f2 * is.z, v3 = f3 * is.w;
        if (v0 > best) { best = v0; bidx = j0; }
        if (v1 > best) { best = v1; bidx = j0 + 1; }
        if (v2 > best) { best = v2; bidx = j0 + 2; }
        if (v3 > best) { best = v3; bidx = j0 + 3; }
    }

    __shared__ float bv[256];
    __shared__ int   bi[256];
    bv[threadIdx.x] = best;
    bi[threadIdx.x] = bidx;
    __syncthreads();
    for (int t = 128; t > 0; t >>= 1) {
        if (threadIdx.x < t) {
            float ov = bv[threadIdx.x + t];
            int   oi = bi[threadIdx.x + t];
            if (ov > bv[threadIdx.x] || (ov == bv[threadIdx.x] && oi < bi[threadIdx.x])) {
                bv[threadIdx.x] = ov;
                bi[threadIdx.x] = oi;
            }
        }
        __syncthreads();
    }
    if (threadIdx.x == 0) idxOut[i] = bi[0];
}

// ---------------- build masked fp16 matrices ----------------
__global__ void k_build(const float* __restrict__ style, const float* __restrict__ input,
                        const float* __restrict__ mask, const int* __restrict__ idx,
                        _Float16* __restrict__ fc, _Float16* __restrict__ fg) {
    int t = blockIdx.x * 256 + threadIdx.x;
    int e0 = t * 8;
    int p0 = e0 & (P - 1), c = e0 >> 12;
    half8 vg, vc;
    #pragma unroll
    for (int u = 0; u < 8; ++u) {
        float m = mask[p0 + u];
        vg[u] = (_Float16)(input[e0 + u] * m);
        vc[u] = (_Float16)(style[(c << 12) + idx[p0 + u]] * m);
    }
    *(half8*)(fg + e0) = vg;
    *(half8*)(fc + e0) = vc;
}

// ---------------- gram diff partials, lower-triangle tiles only (G, T symmetric) ----------------
// blockIdx.x = tile t in [0,10): (bx,by) with by>=bx; blockIdx.z = K-chunk z in [0,16)
__device__ __constant__ int TBX[10] = {0, 0, 1, 0, 1, 2, 0, 1, 2, 3};
__device__ __constant__ int TBY[10] = {0, 1, 1, 2, 2, 2, 3, 3, 3, 3};

__global__ __launch_bounds__(256) void k_gram(const _Float16* __restrict__ fg,
                                              const _Float16* __restrict__ fc,
                                              float* __restrict__ part) {
    const int t = blockIdx.x, z = blockIdx.z;
    const int p0 = z * 256;
    const int wave = threadIdx.x >> 6, lane = threadIdx.x & 63;
    const int wr = wave >> 1, wc = wave & 1, quad = lane >> 4, l15 = lane & 15;
    const int a0 = TBY[t] * 128 + wr * 64, b0 = TBX[t] * 128 + wc * 64;

    f32x4 accg[4][4] = {};
    f32x4 accc[4][4] = {};
    for (int ks = 0; ks < 256; ks += 32) {
        int kbase = p0 + ks + quad * 8;
        half8 af[4], bf[4];
        #pragma unroll
        for (int mi = 0; mi < 4; ++mi) af[mi] = *(const half8*)(fg + (size_t)(a0 + mi * 16 + l15) * P + kbase);
        #pragma unroll
        for (int ni = 0; ni < 4; ++ni) bf[ni] = *(const half8*)(fg + (size_t)(b0 + ni * 16 + l15) * P + kbase);
        #pragma unroll
        for (int mi = 0; mi < 4; ++mi)
            #pragma unroll
            for (int ni = 0; ni < 4; ++ni)
                accg[mi][ni] = __builtin_amdgcn_mfma_f32_16x16x32_f16(af[mi], bf[ni], accg[mi][ni], 0, 0, 0);
        #pragma unroll
        for (int mi = 0; mi < 4; ++mi) af[mi] = *(const half8*)(fc + (size_t)(a0 + mi * 16 + l15) * P + kbase);
        #pragma unroll
        for (int ni = 0; ni < 4; ++ni) bf[ni] = *(const half8*)(fc + (size_t)(b0 + ni * 16 + l15) * P + kbase);
        #pragma unroll
        for (int mi = 0; mi < 4; ++mi)
            #pragma unroll
            for (int ni = 0; ni < 4; ++ni)
                accc[mi][ni] = __builtin_amdgcn_mfma_f32_16x16x32_f16(af[mi], bf[ni], accc[mi][ni], 0, 0, 0);
    }
    float* dst = part + (size_t)(z * 10 + t) * 16384;
    #pragma unroll
    for (int mi = 0; mi < 4; ++mi)
        #pragma unroll
        for (int ni = 0; ni < 4; ++ni)
            #pragma unroll
            for (int r = 0; r < 4; ++r)
                dst[(wr * 64 + mi * 16 + quad * 4 + r) * 128 + wc * 64 + ni * 16 + l15]
                    = accg[mi][ni][r] - accc[mi][ni][r];
}

// ---------------- loss partials: w[t]*(sum_z part)^2, plain store (no atomics/init) ----------------
__global__ void k_loss(const float* __restrict__ part, float* __restrict__ lsum) {
    int e = blockIdx.x * 256 + threadIdx.x;       // 640 blocks x 256 = 163840 = 10*16384
    int t = e >> 14, loc = e & 16383;
    float d = 0.f;
    #pragma unroll
    for (int z = 0; z < 16; ++z) d += part[(size_t)(z * 10 + t) * 16384 + loc];
    float w = (TBX[t] == TBY[t]) ? 1.0f : 2.0f;
    __shared__ float red[256];
    red[threadIdx.x] = d * d * w;
    __syncthreads();
    for (int s = 128; s > 0; s >>= 1) {
        if (threadIdx.x < s) red[threadIdx.x] += red[threadIdx.x + s];
        __syncthreads();
    }
    if (threadIdx.x == 0) lsum[blockIdx.x] = red[0];
}

__global__ void k_final(const float* __restrict__ lsum, const float* __restrict__ msum,
                        float* __restrict__ out) {
    __shared__ float red[256];
    float s = 0.f;
    for (int e = threadIdx.x; e < 640; e += 256) s += lsum[e];
    red[threadIdx.x] = s;
    __syncthreads();
    for (int t = 128; t > 0; t >>= 1) {
        if (threadIdx.x < t) red[threadIdx.x] += red[threadIdx.x + t];
        __syncthreads();
    }
    if (threadIdx.x == 0) {
        float m = msum[0];
        out[0] = red[0] * 100.0f / (m * m * 262144.0f);
    }
}

extern "C" void kernel_launch(void* const* d_in, const int* in_sizes, int n_in,
                              void* d_out, int out_size, void* d_ws, size_t ws_size,
                              hipStream_t stream) {
    (void)in_sizes; (void)n_in; (void)out_size; (void)ws_size;
    const float* content = (const float*)d_in[0];
    const float* style   = (const float*)d_in[1];
    const float* input   = (const float*)d_in[2];
    const float* mask    = (const float*)d_in[3];

    char* ws = (char*)d_ws;
    _Float16* Eb   = (_Float16*)ws;                        // 32 MB (dead after k_argmax)
    float*    part = (float*)ws;                           // 10.5 MB (overlays Eb)
    _Float16* Ah   = (_Float16*)(ws + (32u << 20));        // 4 MB
    _Float16* Bh   = (_Float16*)(ws + (36u << 20));        // 4 MB
    _Float16* fg_h = (_Float16*)(ws + (40u << 20));        // 4 MB
    _Float16* fc_h = (_Float16*)(ws + (44u << 20));        // 4 MB
    float*    small = (float*)(ws + (48u << 20));
    float* sqn_part = small;               // 8*4096
    float* inv_sn   = small + 32768;       // 4096
    float* msum     = small + 36864;
    float* lsum     = small + 36992;       // 640
    int*   idx      = (int*)(small + 37888);
    float* out = (float*)d_out;

    k_prep  <<<512, 256, 0, stream>>>(content, style, Ah, Bh, sqn_part);
    k_pnorm <<<16, 256, 0, stream>>>(sqn_part, mask, inv_sn, msum);
    k_gemm16<<<dim3(32, 32), 256, 0, stream>>>(Ah, Bh, Eb);
    k_argmax<<<4096, 256, 0, stream>>>(Eb, inv_sn, idx);
    k_build <<<1024, 256, 0, stream>>>(style, input, mask, idx, fc_h, fg_h);
    k_gram  <<<dim3(10, 1, 16), 256, 0, stream>>>(fg_h, fc_h, part);
    k_loss  <<<640, 256, 0, stream>>>(part, lsum);
    k_final <<<1, 256, 0, stream>>>(lsum, msum, out);
}